// Round 7
// baseline (373.343 us; speedup 1.0000x reference)
//
#include <hip/hip_runtime.h>

// SwinV2 window attention — round 7: round-6 structure with FIXED ws offsets
// (qbuf/kbuf are 64 MiB each, not 32 — overlap was clobbering batch b=1).
// 512-thr blocks, wave=head, batched B-loads, dense layouts, one barrier/kernel.
// ws layout: [0,128K) biasfrag f32 | [128K,512K) w_t fp16[768][256]
//   | [512K,640K) p_t fp16[256][256] | @1M qbuf 64M | kbuf 64M | vtbuf 64M
// qbuf/kbuf: [b*1024+win][h][qq 64][ch 32] f16 ; vtbuf: [(b*1024+win)*8+h][kb 8][u 32][kk 8]

typedef _Float16 f16;
typedef _Float16 f16x4 __attribute__((ext_vector_type(4)));
typedef _Float16 f16x8 __attribute__((ext_vector_type(8)));
typedef float f32x4 __attribute__((ext_vector_type(4)));

#define LOG100 4.6051701859880914f
#define EPS_L2 1.55e-5f

__device__ __forceinline__ int seg2(int p) { return (p >= 248) + (p >= 252); }

// ---------------- prep: CPB bias (MFMA C-frag order) + weight transpose/convert
__global__ __launch_bounds__(512) void k_prep(
    const float* __restrict__ cpb_w1, const float* __restrict__ cpb_b1,
    const float* __restrict__ cpb_w2, const float* __restrict__ qkv_w,
    const float* __restrict__ proj_w,
    float* __restrict__ biasfrag, f16* __restrict__ w_t, f16* __restrict__ p_t)
{
    __shared__ float cpb[225 * 8];
    int tid = threadIdx.x;
    if (blockIdx.x == 0) {
        if (tid < 225) {
            int a = tid / 15, b2 = tid % 15;
            float xa = (float)(a - 7) * (8.0f / 7.0f);
            float xb = (float)(b2 - 7) * (8.0f / 7.0f);
            float t0 = (xa < 0.f ? -1.f : 1.f) * log2f(1.0f + fabsf(xa)) * (1.0f / 3.0f);
            float t1 = (xb < 0.f ? -1.f : 1.f) * log2f(1.0f + fabsf(xb)) * (1.0f / 3.0f);
            float acc[8] = {0.f, 0.f, 0.f, 0.f, 0.f, 0.f, 0.f, 0.f};
            for (int j = 0; j < 512; ++j) {
                float hh = t0 * cpb_w1[j] + t1 * cpb_w1[512 + j] + cpb_b1[j];
                hh = fmaxf(hh, 0.0f);
                #pragma unroll
                for (int h = 0; h < 8; ++h) acc[h] += hh * cpb_w2[j * 8 + h];
            }
            #pragma unroll
            for (int h = 0; h < 8; ++h) cpb[tid * 8 + h] = acc[h];
        }
        __syncthreads();
        for (int f = tid; f < 32768; f += 512) {
            int r = f & 3, lane = (f >> 2) & 63, nt = (f >> 8) & 3, mt = (f >> 10) & 3, h = (f >> 12) & 7;
            int q = mt * 16 + ((lane >> 4) << 2) + r;
            int k = nt * 16 + (lane & 15);
            int idx = ((q >> 3) - (k >> 3) + 7) * 15 + ((q & 7) - (k & 7) + 7);
            float c = cpb[idx * 8 + h];
            biasfrag[f] = 16.0f / (1.0f + expf(-c));
        }
    } else {
        int base = (blockIdx.x - 1) * 512 + tid;
        const int stride = 128 * 512;
        for (int i = base; i < 768 * 256; i += stride) {
            int n = i >> 8, k = i & 255;
            w_t[i] = (f16)qkv_w[k * 768 + n];     // w_t[n][k] = W[k][n]
        }
        for (int i = base; i < 256 * 256; i += stride) {
            int n = i >> 8, k = i & 255;
            p_t[i] = (f16)proj_w[k * 256 + n];
        }
    }
}

// ---------------- K1: qkv GEMM. Block = 64 rolled pixels, 8 waves, wave = head.
// Wave h does strips (q,h),(k,h),(v,h) with batched B-frag loads.
__global__ __launch_bounds__(512, 2) void k_qkv(
    const float* __restrict__ x, const f16* __restrict__ w_t,
    const float* __restrict__ q_bias, const float* __restrict__ v_bias,
    const float* __restrict__ scale,
    f16* __restrict__ qbuf, f16* __restrict__ kbuf, f16* __restrict__ vtbuf)
{
    __shared__ char L[65536];                 // [0,32K) x-tile; [32K,64K) 8x4K wave bounce
    const int tid = threadIdx.x;
    const int lane = tid & 63;
    const int h = tid >> 6;                   // wave = head
    const int l15 = lane & 15, g = lane >> 4;
    const int bid = blockIdx.x;
    const int b = bid >> 10, bid2 = bid & 1023;
    const int ip = bid2 >> 2;                 // rolled image row
    const int jp0 = (bid2 & 3) << 6;          // rolled col base
    const int kb = ip & 7;
    const int iwin = ip >> 3;
    char* wb = L + 32768 + (h << 12);
    const f32x4 fz = {0.f, 0.f, 0.f, 0.f};

    // ---- stage x (rolled coords): 64 pixels x 256 ch, f32 -> f16, swizzled
    {
        int row = tid >> 3, tc = tid & 7;
        int ix = (ip + 4) & 255;
        int jx = (jp0 + row + 4) & 255;
        const float* xr = x + ((((long)b << 8) + ix) * 256 + jx) * 256;
        int swz = (row & 7) << 4;
        #pragma unroll
        for (int rep = 0; rep < 4; ++rep) {
            int ch = rep * 64 + tc * 8;
            float4 v0 = *reinterpret_cast<const float4*>(xr + ch);
            float4 v1 = *reinterpret_cast<const float4*>(xr + ch + 4);
            f16x8 hv = { (f16)v0.x, (f16)v0.y, (f16)v0.z, (f16)v0.w,
                         (f16)v1.x, (f16)v1.y, (f16)v1.z, (f16)v1.w };
            *reinterpret_cast<f16x8*>(L + ((row * 512 + ch * 2) ^ swz)) = hv;
        }
    }
    __syncthreads();   // the ONLY block barrier

    #pragma unroll 1
    for (int p = 0; p < 3; ++p) {
        const int s = (p << 3) + h;           // w_t strip (32 cols at s*32)
        // batched B-frag loads: 16 in flight
        f16x8 bb[16];
        #pragma unroll
        for (int ks = 0; ks < 8; ++ks)
            #pragma unroll
            for (int nt = 0; nt < 2; ++nt)
                bb[ks * 2 + nt] = *reinterpret_cast<const f16x8*>(
                    w_t + (s * 32 + nt * 16 + l15) * 256 + ks * 32 + g * 8);

        f32x4 acc[4][2];
        #pragma unroll
        for (int mt = 0; mt < 4; ++mt) { acc[mt][0] = fz; acc[mt][1] = fz; }
        #pragma unroll
        for (int ks = 0; ks < 8; ++ks) {
            f16x8 a[4];
            #pragma unroll
            for (int mt = 0; mt < 4; ++mt) {
                int row = mt * 16 + l15;
                a[mt] = *reinterpret_cast<const f16x8*>(
                    L + ((row * 512 + ks * 64 + g * 16) ^ ((row & 7) << 4)));
            }
            #pragma unroll
            for (int mt = 0; mt < 4; ++mt)
                #pragma unroll
                for (int nt = 0; nt < 2; ++nt)
                    acc[mt][nt] = __builtin_amdgcn_mfma_f32_16x16x32_f16(a[mt], bb[ks * 2 + nt], acc[mt][nt], 0, 0, 0);
        }

        if (p < 2) {
            // q/k: (+bias), l2norm, (q: *logit_scale) -> bounce [pix 64][ch 32]
            float ls = 1.0f, b0 = 0.f, b1 = 0.f;
            if (p == 0) {
                ls = __expf(fminf(scale[h], LOG100));
                b0 = q_bias[(h << 5) + l15];
                b1 = q_bias[(h << 5) + 16 + l15];
            }
            #pragma unroll
            for (int mt = 0; mt < 4; ++mt)
                #pragma unroll
                for (int r = 0; r < 4; ++r) {
                    float a0 = acc[mt][0][r] + b0, a1 = acc[mt][1][r] + b1;
                    float s2 = a0 * a0 + a1 * a1;
                    s2 += __shfl_xor(s2, 1); s2 += __shfl_xor(s2, 2);
                    s2 += __shfl_xor(s2, 4); s2 += __shfl_xor(s2, 8);
                    float iv = ls / sqrtf(fmaxf(s2, EPS_L2));
                    int row = mt * 16 + (g << 2) + r;
                    int swz = (row & 3) << 4;
                    *reinterpret_cast<f16*>(wb + ((row * 64 + l15 * 2) ^ swz)) = (f16)(a0 * iv);
                    *reinterpret_cast<f16*>(wb + ((row * 64 + 32 + l15 * 2) ^ swz)) = (f16)(a1 * iv);
                }
            // coalesced store: 512B contiguous per instr, layout [bw][h][qq][32]
            f16* dst = p ? kbuf : qbuf;
            #pragma unroll
            for (int i = 0; i < 8; ++i) {
                int row = i * 8 + (lane >> 3);
                int c4 = (lane & 7) * 4;
                f16x4 vv = *reinterpret_cast<const f16x4*>(
                    wb + ((row * 64 + c4 * 2) ^ ((row & 3) << 4)));
                int win = (iwin << 5) | ((jp0 >> 3) + i);
                int qq = (kb << 3) + (lane >> 3);
                *reinterpret_cast<f16x4*>(
                    dst + (((long)((b << 10) | win)) * 8 + h) * 2048 + qq * 32 + c4) = vv;
            }
        } else {
            // v: +bias -> bounce transposed [u 32][pix 64], f16x4 writes over r
            float b0 = v_bias[(h << 5) + l15], b1 = v_bias[(h << 5) + 16 + l15];
            #pragma unroll
            for (int mt = 0; mt < 4; ++mt)
                #pragma unroll
                for (int nt = 0; nt < 2; ++nt) {
                    float bsel = nt ? b1 : b0;
                    f16x4 pk = { (f16)(acc[mt][nt][0] + bsel), (f16)(acc[mt][nt][1] + bsel),
                                 (f16)(acc[mt][nt][2] + bsel), (f16)(acc[mt][nt][3] + bsel) };
                    int u = nt * 16 + l15;
                    int pix0 = mt * 16 + (g << 2);
                    *reinterpret_cast<f16x4*>(wb + ((u * 128 + pix0 * 2) ^ ((u & 7) << 4))) = pk;
                }
            // store: per window contiguous 512B ([u 32][kk 8])
            #pragma unroll
            for (int w2 = 0; w2 < 8; ++w2) {
                int u = lane >> 1, kk = (lane & 1) * 4;
                f16x4 vv = *reinterpret_cast<const f16x4*>(
                    wb + ((u * 128 + (w2 * 8 + kk) * 2) ^ ((u & 7) << 4)));
                int win = (iwin << 5) | ((jp0 >> 3) + w2);
                *reinterpret_cast<f16x4*>(
                    vtbuf + (((long)((b << 10) | win)) * 8 + h) * 2048 + kb * 256 + u * 8 + kk) = vv;
            }
        }
    }
}

// ---------------- K2: per-window attention + fused proj. 8 waves, wave = head.
__global__ __launch_bounds__(512, 2) void k_attn_proj(
    const f16* __restrict__ qbuf, const f16* __restrict__ kbuf,
    const f16* __restrict__ vtbuf, const float* __restrict__ biasfrag,
    const f16* __restrict__ p_t, const float* __restrict__ proj_b,
    float* __restrict__ out)
{
    __shared__ char L[65536];                 // [0,32K) ot[64][256] f16; [32K,64K) bounce
    const int tid = threadIdx.x;
    const int lane = tid & 63;
    const int h = tid >> 6;                   // wave = head
    const int l15 = lane & 15, g = lane >> 4;
    const int bw = blockIdx.x;
    const int win = bw & 1023, bb = bw >> 10;
    const int wh = win >> 5, ww = win & 31;
    char* wb = L + 32768 + (h << 12);
    const f32x4 fz = {0.f, 0.f, 0.f, 0.f};
    const bool boundary = (wh == 31) || (ww == 31);

    const f16* qp = qbuf + ((long)bw * 8 + h) * 2048;
    const f16* kp = kbuf + ((long)bw * 8 + h) * 2048;
    const f16* vp = vtbuf + ((long)bw * 8 + h) * 2048;

    // hoist ALL inputs: 12 independent loads in flight
    f16x8 qa[4], kb[4], vf[2][2];
    #pragma unroll
    for (int t = 0; t < 4; ++t) {
        qa[t] = *reinterpret_cast<const f16x8*>(qp + (t * 16 + l15) * 32 + g * 8);
        kb[t] = *reinterpret_cast<const f16x8*>(kp + (t * 16 + l15) * 32 + g * 8);
    }
    #pragma unroll
    for (int nt = 0; nt < 2; ++nt)
        #pragma unroll
        for (int ks = 0; ks < 2; ++ks)
            vf[nt][ks] = *reinterpret_cast<const f16x8*>(
                vp + (ks * 4 + g) * 256 + (nt * 16 + l15) * 8);

    // ---- S + bias (+mask), softmax (1/sum folded into P), pack
    f16x4 ph[4][4];
    #pragma unroll
    for (int mt = 0; mt < 4; ++mt) {
        f32x4 sr[4];
        #pragma unroll
        for (int nt = 0; nt < 4; ++nt)
            sr[nt] = __builtin_amdgcn_mfma_f32_16x16x32_f16(qa[mt], kb[nt], fz, 0, 0, 0);
        #pragma unroll
        for (int nt = 0; nt < 4; ++nt)
            sr[nt] += *reinterpret_cast<const f32x4*>(
                biasfrag + ((((h * 4 + mt) * 4 + nt) * 64 + lane) << 2));
        if (boundary) {
            #pragma unroll
            for (int r = 0; r < 4; ++r) {
                int q = mt * 16 + (g << 2) + r;
                int lq = seg2((wh << 3) + (q >> 3)) * 3 + seg2((ww << 3) + (q & 7));
                #pragma unroll
                for (int nt = 0; nt < 4; ++nt) {
                    int k = nt * 16 + l15;
                    int lk = seg2((wh << 3) + (k >> 3)) * 3 + seg2((ww << 3) + (k & 7));
                    if (lq != lk) sr[nt][r] -= 100.0f;
                }
            }
        }
        #pragma unroll
        for (int r = 0; r < 4; ++r) {
            float mx = fmaxf(fmaxf(sr[0][r], sr[1][r]), fmaxf(sr[2][r], sr[3][r]));
            mx = fmaxf(mx, __shfl_xor(mx, 1));
            mx = fmaxf(mx, __shfl_xor(mx, 2));
            mx = fmaxf(mx, __shfl_xor(mx, 4));
            mx = fmaxf(mx, __shfl_xor(mx, 8));
            float sm = 0.f;
            #pragma unroll
            for (int nt = 0; nt < 4; ++nt) {
                float e = __expf(sr[nt][r] - mx);
                sr[nt][r] = e;
                sm += e;
            }
            sm += __shfl_xor(sm, 1); sm += __shfl_xor(sm, 2);
            sm += __shfl_xor(sm, 4); sm += __shfl_xor(sm, 8);
            float inv = 1.0f / sm;
            #pragma unroll
            for (int nt = 0; nt < 4; ++nt) sr[nt][r] *= inv;
        }
        #pragma unroll
        for (int nt = 0; nt < 4; ++nt)
            ph[mt][nt] = f16x4{ (f16)sr[nt][0], (f16)sr[nt][1], (f16)sr[nt][2], (f16)sr[nt][3] };
    }

    // ---- PV in two 32-key halves via wave-private 4K bounce (P already normalized)
    f32x4 o[4][2];
    #pragma unroll
    for (int mt = 0; mt < 4; ++mt) { o[mt][0] = fz; o[mt][1] = fz; }
    #pragma unroll
    for (int half = 0; half < 2; ++half) {
        #pragma unroll
        for (int mt = 0; mt < 4; ++mt)
            #pragma unroll
            for (int nt2 = 0; nt2 < 2; ++nt2)
                #pragma unroll
                for (int r = 0; r < 4; ++r) {
                    int q = mt * 16 + (g << 2) + r;
                    int key = nt2 * 16 + l15;
                    *reinterpret_cast<f16*>(wb + ((q * 64 + key * 2) ^ ((q & 3) << 4))) =
                        ph[mt][half * 2 + nt2][r];
                }
        #pragma unroll
        for (int mt = 0; mt < 4; ++mt) {
            int q = mt * 16 + l15;
            f16x8 pa = *reinterpret_cast<const f16x8*>(
                wb + ((q * 64 + g * 16) ^ ((q & 3) << 4)));
            #pragma unroll
            for (int nt = 0; nt < 2; ++nt)
                o[mt][nt] = __builtin_amdgcn_mfma_f32_16x16x32_f16(pa, vf[nt][half], o[mt][nt], 0, 0, 0);
        }
    }

    // ---- O -> ot strip (already normalized)
    #pragma unroll
    for (int mt = 0; mt < 4; ++mt)
        #pragma unroll
        for (int r = 0; r < 4; ++r) {
            int q = mt * 16 + (g << 2) + r;
            #pragma unroll
            for (int nt = 0; nt < 2; ++nt) {
                int ch = (h << 5) + nt * 16 + l15;
                *reinterpret_cast<f16*>(L + ((q * 512 + ch * 2) ^ ((q & 7) << 4))) =
                    (f16)o[mt][nt][r];
            }
        }
    __syncthreads();   // the ONLY block barrier

    // ---- fused proj: wave h does ch strip h*32
    const int c0 = h << 5;
    f32x4 pc[4][2];
    #pragma unroll
    for (int mt = 0; mt < 4; ++mt) { pc[mt][0] = fz; pc[mt][1] = fz; }
    #pragma unroll
    for (int ks = 0; ks < 8; ++ks) {
        f16x8 a[4], bfr[2];
        #pragma unroll
        for (int mt = 0; mt < 4; ++mt) {
            int q = mt * 16 + l15;
            a[mt] = *reinterpret_cast<const f16x8*>(
                L + ((q * 512 + ks * 64 + g * 16) ^ ((q & 7) << 4)));
        }
        #pragma unroll
        for (int nt = 0; nt < 2; ++nt)
            bfr[nt] = *reinterpret_cast<const f16x8*>(
                p_t + (c0 + nt * 16 + l15) * 256 + ks * 32 + g * 8);
        #pragma unroll
        for (int mt = 0; mt < 4; ++mt)
            #pragma unroll
            for (int nt = 0; nt < 2; ++nt)
                pc[mt][nt] = __builtin_amdgcn_mfma_f32_16x16x32_f16(a[mt], bfr[nt], pc[mt][nt], 0, 0, 0);
    }
    float pb0 = proj_b[c0 + l15], pb1 = proj_b[c0 + 16 + l15];
    #pragma unroll
    for (int mt = 0; mt < 4; ++mt)
        #pragma unroll
        for (int r = 0; r < 4; ++r) {
            int q = mt * 16 + (g << 2) + r;
            int i = ((wh << 3) + (q >> 3) + 4) & 255;   // roll(+4) un-partition
            int j = ((ww << 3) + (q & 7) + 4) & 255;
            long addr = (((long)bb * 256 + i) * 256 + j) * 256;
            out[addr + c0 + l15]      = pc[mt][0][r] + pb0;
            out[addr + c0 + 16 + l15] = pc[mt][1][r] + pb1;
        }
}

extern "C" void kernel_launch(void* const* d_in, const int* in_sizes, int n_in,
                              void* d_out, int out_size, void* d_ws, size_t ws_size,
                              hipStream_t stream) {
    const float* x      = (const float*)d_in[0];
    const float* qkv_w  = (const float*)d_in[1];
    const float* q_bias = (const float*)d_in[2];
    const float* v_bias = (const float*)d_in[3];
    const float* scale  = (const float*)d_in[4];
    const float* cpb_w1 = (const float*)d_in[5];
    const float* cpb_b1 = (const float*)d_in[6];
    const float* cpb_w2 = (const float*)d_in[7];
    const float* proj_w = (const float*)d_in[8];
    const float* proj_b = (const float*)d_in[9];
    float* out = (float*)d_out;

    char* ws = (char*)d_ws;
    float* biasfrag = (float*)(ws);                         // 128 KiB
    f16* w_t  = (f16*)(ws + 131072);                        // 384 KiB
    f16* p_t  = (f16*)(ws + 524288);                        // 128 KiB
    f16* qbuf = (f16*)(ws + (1u << 20));                    // 64 MiB
    f16* kbuf = (f16*)(ws + (1u << 20) + (1u << 26));       // 64 MiB
    f16* vtbuf = (f16*)(ws + (1u << 20) + 2u * (1u << 26)); // 64 MiB

    hipLaunchKernelGGL(k_prep, dim3(129), dim3(512), 0, stream,
                       cpb_w1, cpb_b1, cpb_w2, qkv_w, proj_w, biasfrag, w_t, p_t);
    hipLaunchKernelGGL(k_qkv, dim3(2048), dim3(512), 0, stream,
                       x, w_t, q_bias, v_bias, scale, qbuf, kbuf, vtbuf);
    hipLaunchKernelGGL(k_attn_proj, dim3(2048), dim3(512), 0, stream,
                       qbuf, kbuf, vtbuf, biasfrag, p_t, proj_b, out);
}